// Round 11
// baseline (535.432 us; speedup 1.0000x reference)
//
#include <hip/hip_runtime.h>
#include <hip/hip_bf16.h>
#include <math.h>

#define DD 128
#define HH 4
#define NEG_SLOPE 0.2f
#define LN_EPS 1e-5f

typedef __attribute__((ext_vector_type(8))) short bf16x8;
typedef __attribute__((ext_vector_type(8))) unsigned short us16x8;
typedef __attribute__((ext_vector_type(4))) float f32x4;

__device__ __forceinline__ float lrelu(float e) { return fmaxf(e, NEG_SLOPE * e); }
__device__ __forceinline__ float bflo(unsigned u) { return __uint_as_float(u << 16); }
__device__ __forceinline__ float bfhi(unsigned u) { return __uint_as_float(u & 0xFFFF0000u); }
__device__ __forceinline__ unsigned short f2bf(float f) {
    return __builtin_bit_cast(unsigned short, __float2bfloat16(f));
}

// ---------------- W transpose + zero deg/bpart (one dispatch) ----------------
// blocks 0..7: WTb[col][k] = bf16(W[k][col]); blocks 8..8+zb-1: zero deg;
// block 8+zb: zero bpart.

__global__ __launch_bounds__(256) void wtrans_zero(const float* __restrict__ W,
                                                   unsigned short* __restrict__ WTb,
                                                   int* __restrict__ deg,
                                                   int* __restrict__ bpart,
                                                   int n, int nb, int zb) {
    int b = blockIdx.x;
    int t = threadIdx.x;
    if (b < 8) {
        __shared__ float tile[16][128];
#pragma unroll
        for (int i = 0; i < 8; i++) {
            int flat = i * 256 + t;          // coalesced read of 16x128 slab
            int kk = flat >> 7, colc = flat & 127;
            tile[kk][colc] = W[(b * 16 + kk) * DD + colc];
        }
        __syncthreads();
        int colc = t & 127, half = t >> 7;
        us16x8 tmp;
#pragma unroll
        for (int kk = 0; kk < 8; kk++) tmp[kk] = f2bf(tile[half * 8 + kk][colc]);
        *(uint4*)&WTb[colc * DD + b * 16 + half * 8] = __builtin_bit_cast(uint4, tmp);
    } else if (b < 8 + zb) {
        int base = (b - 8) * 1024 + t;
#pragma unroll
        for (int i = 0; i < 4; i++) {
            int idx = base + i * 256;
            if (idx < n) deg[idx] = 0;
        }
    } else {
        if (t < nb) bpart[t] = 0;
    }
}

// ---------------- CSR count: deg + per-scan-block partials in one pass ----------------

__global__ __launch_bounds__(256) void count_kernel(const int* __restrict__ ei,
                                                    int* __restrict__ deg,
                                                    int* __restrict__ bpart, int E) {
    int i = blockIdx.x * 256 + threadIdx.x;
    if (i < E) {
        int d = ei[E + i];                  // dst = ei[1][i]
        atomicAdd(&deg[d], 1);
        atomicAdd(&bpart[d >> 8], 1);       // 256 nodes per writeoff block
    }
}

// ---------------- writeoff: self-scan of bpart + in-block scan of deg ----------------

__global__ __launch_bounds__(256) void writeoff_kernel(const int* __restrict__ deg,
                                                       const int* __restrict__ bpart,
                                                       int* __restrict__ rowstart,
                                                       int* __restrict__ cursor, int n, int E) {
    __shared__ int addsh;
    __shared__ int ws[4];
    int t = threadIdx.x;
    // wave 0: exclusive prefix of bpart over preceding blocks
    if (t < 64) {
        int s = 0;
        for (int i = t; i < blockIdx.x; i += 64) s += bpart[i];
#pragma unroll
        for (int m = 1; m < 64; m <<= 1) s += __shfl_xor(s, m);
        if (t == 0) addsh = s;
    }
    int i = blockIdx.x * 256 + t;
    int v = (i < n) ? deg[i] : 0;
    int x = v;
#pragma unroll
    for (int m = 1; m < 64; m <<= 1) {
        int y = __shfl_up(x, m);
        if ((t & 63) >= m) x += y;
    }
    if ((t & 63) == 63) ws[t >> 6] = x;
    __syncthreads();
    int add = addsh;
    for (int w = 0; w < (t >> 6); w++) add += ws[w];
    int excl = x - v + add;
    if (i < n) { rowstart[i] = excl; cursor[i] = excl; }
    if (i == 0) rowstart[n] = E;
}

// fill CSR: one 16B record per edge {src, pe01(bf16x2), pe23(bf16x2), 0}
// pe = exp(lrelu(aS[src]+aD[dst])), unnormalized (|logit|<=~6 -> f32 exp safe;
// softmax is shift-invariant so no max pass needed).
__global__ __launch_bounds__(256) void fill_kernel(const int* __restrict__ ei,
                            const float* __restrict__ aS, const float* __restrict__ aD,
                            int* __restrict__ cursor, uint4* __restrict__ recbuf, int E) {
    int i = blockIdx.x * 256 + threadIdx.x;
    if (i >= E) return;
    int s = ei[i];
    int d = ei[E + i];
    int pos = atomicAdd(&cursor[d], 1);
    float4 sv = ((const float4*)aS)[s];
    float4 dv = ((const float4*)aD)[d];
    float p0 = __expf(lrelu(sv.x + dv.x));
    float p1 = __expf(lrelu(sv.y + dv.y));
    float p2 = __expf(lrelu(sv.z + dv.z));
    float p3 = __expf(lrelu(sv.w + dv.w));
    uint4 rec;
    rec.x = (unsigned)s;
    rec.y = (unsigned)f2bf(p0) | ((unsigned)f2bf(p1) << 16);
    rec.z = (unsigned)f2bf(p2) | ((unsigned)f2bf(p3) << 16);
    rec.w = 0;
    recbuf[pos] = rec;
}

// ---------------- MFMA GEMM + register-only fused logits ----------------
// Hb(bf16) = X @ W (round-2-verified core, direct scattered Hb stores).
// Logits fused via cross-lane shfl reduction over acc registers (NO LDS reuse):
// lane (q,l15) holds acc[c][r] = D[R+q*4+r][c*16+l15]; head of col c*16+l15 is c>>1.

__global__ __launch_bounds__(256) void gemm_mfma(const float* __restrict__ X,
                                                 const unsigned short* __restrict__ WTb,
                                                 const float* __restrict__ attS,
                                                 const float* __restrict__ attD,
                                                 unsigned short* __restrict__ Hb,
                                                 float* __restrict__ aS,
                                                 float* __restrict__ aD,
                                                 float* __restrict__ pSelf, int n) {
    __shared__ unsigned short lds[DD * DD];   // 32 KB, [col][k] bf16, XOR-swizzled
    int t = threadIdx.x;
    const uint4* src = (const uint4*)WTb;
#pragma unroll
    for (int i = 0; i < 8; i++) {
        int b = i * 256 + t;                  // 16B block index
        uint4 v = src[b];
        int byteaddr = b * 16;
        int col = b >> 4;
        int swz = byteaddr ^ ((col & 15) << 4);
        *(uint4*)((char*)lds + swz) = v;
    }
    __syncthreads();

    int w = t >> 6, l = t & 63;
    int R = blockIdx.x * 64 + w * 16;
    int l15 = l & 15, q = l >> 4;
    int rclamp = min(R + l15, n - 1);

    f32x4 acc[8];
#pragma unroll
    for (int c = 0; c < 8; c++) acc[c] = (f32x4){0.f, 0.f, 0.f, 0.f};

#pragma unroll
    for (int ks = 0; ks < 4; ks++) {
        // A-frag: row = l&15, k = ks*32 + q*8 + i (8 contiguous k per lane)
        const float* ap = X + (long)rclamp * DD + ks * 32 + q * 8;
        float4 a0 = *(const float4*)ap;
        float4 a1 = *(const float4*)(ap + 4);
        bf16x8 af;
        af[0] = (short)f2bf(a0.x); af[1] = (short)f2bf(a0.y);
        af[2] = (short)f2bf(a0.z); af[3] = (short)f2bf(a0.w);
        af[4] = (short)f2bf(a1.x); af[5] = (short)f2bf(a1.y);
        af[6] = (short)f2bf(a1.z); af[7] = (short)f2bf(a1.w);
#pragma unroll
        for (int c = 0; c < 8; c++) {
            int col = c * 16 + l15;
            int byteaddr = col * 256 + ks * 64 + q * 16;
            int swz = byteaddr ^ ((col & 15) << 4);
            bf16x8 bfr = *(const bf16x8*)((const char*)lds + swz);
            acc[c] = __builtin_amdgcn_mfma_f32_16x16x32_bf16(af, bfr, acc[c], 0, 0, 0);
        }
    }

    // Hb store (verified round-2 path): col = c*16+l15, row = R + q*4 + r
    int rowbase = R + q * 4;
#pragma unroll
    for (int c = 0; c < 8; c++) {
        int colw = c * 16 + l15;
#pragma unroll
        for (int r = 0; r < 4; r++) {
            int orow = rowbase + r;
            if (orow < n) Hb[(long)orow * DD + colw] = f2bf(acc[c][r]);
        }
    }

    // ---- fused logits: register-only, all indices compile-time ----
    float attSl[8], attDl[8];
#pragma unroll
    for (int h = 0; h < 4; h++) {
        attSl[2 * h]     = attS[h * 32 + l15];        // col c=2h   -> 32h+l15
        attSl[2 * h + 1] = attS[h * 32 + 16 + l15];   // col c=2h+1 -> 32h+16+l15
        attDl[2 * h]     = attD[h * 32 + l15];
        attDl[2 * h + 1] = attD[h * 32 + 16 + l15];
    }
    float sA[4][4], sD[4][4];   // [r][h], unrolled indices only
#pragma unroll
    for (int r = 0; r < 4; r++)
#pragma unroll
        for (int h = 0; h < 4; h++) {
            sA[r][h] = acc[2 * h][r] * attSl[2 * h] + acc[2 * h + 1][r] * attSl[2 * h + 1];
            sD[r][h] = acc[2 * h][r] * attDl[2 * h] + acc[2 * h + 1][r] * attDl[2 * h + 1];
        }
    // reduce over the 16-lane l15 group (masks 1,2,4,8 stay inside the group)
#pragma unroll
    for (int m = 1; m < 16; m <<= 1)
#pragma unroll
        for (int r = 0; r < 4; r++)
#pragma unroll
            for (int h = 0; h < 4; h++) {
                sA[r][h] += __shfl_xor(sA[r][h], m);
                sD[r][h] += __shfl_xor(sD[r][h], m);
            }
    // writer lane l15==r stores row R + q*4 + r (float4 over heads)
#pragma unroll
    for (int r = 0; r < 4; r++) {
        if (l15 == r) {
            int node = rowbase + r;
            if (node < n) {
                float4 s4 = make_float4(sA[r][0], sA[r][1], sA[r][2], sA[r][3]);
                float4 d4 = make_float4(sD[r][0], sD[r][1], sD[r][2], sD[r][3]);
                float4 p4;
                p4.x = __expf(lrelu(s4.x + d4.x));
                p4.y = __expf(lrelu(s4.y + d4.y));
                p4.z = __expf(lrelu(s4.z + d4.z));
                p4.w = __expf(lrelu(s4.w + d4.w));
                *(float4*)&aS[node * HH] = s4;
                *(float4*)&aD[node * HH] = d4;
                *(float4*)&pSelf[node * HH] = p4;
            }
        }
    }
}

// ---------------- aggregation + softmax-normalize + GELU + LN + residual ----------------
// ONE wave per node; lane owns channels (2*lane, 2*lane+1); head = lane>>4. Unroll-4.
// Edge stream: one uniform 16B record per edge (broadcast load).

__device__ __forceinline__ float pe_of(uint4 r, int hh) {
    unsigned wd = (hh & 2) ? r.z : r.y;
    return (hh & 1) ? bfhi(wd) : bflo(wd);
}

__global__ __launch_bounds__(256) void agg_kernel(const unsigned* __restrict__ Hb2,
                                                  const float* __restrict__ pSelf,
                                                  const uint4* __restrict__ recbuf,
                                                  const int* __restrict__ rowstart,
                                                  const float* __restrict__ X,
                                                  const float* __restrict__ bias,
                                                  const float* __restrict__ gamma,
                                                  const float* __restrict__ beta,
                                                  float* __restrict__ out, int n) {
    int node = blockIdx.x * 4 + (threadIdx.x >> 6);
    if (node >= n) return;                 // wave-uniform exit; no barriers used
    int lane = threadIdx.x & 63;
    int hh = lane >> 4;

    int rs = rowstart[node];
    int re = rowstart[node + 1];

    float p = pSelf[node * HH + hh];
    unsigned hv = Hb2[(long)node * 64 + lane];
    float d0 = p, ax0 = p * bflo(hv), ay0 = p * bfhi(hv);
    float d1 = 0.f, ax1 = 0.f, ay1 = 0.f;
    float d2 = 0.f, ax2 = 0.f, ay2 = 0.f;
    float d3 = 0.f, ax3 = 0.f, ay3 = 0.f;

    int k = rs;
    for (; k + 4 <= re; k += 4) {
        uint4 r0 = recbuf[k];
        uint4 r1 = recbuf[k + 1];
        uint4 r2 = recbuf[k + 2];
        uint4 r3 = recbuf[k + 3];
        float p0 = pe_of(r0, hh), p1 = pe_of(r1, hh);
        float p2 = pe_of(r2, hh), p3 = pe_of(r3, hh);
        unsigned g0 = Hb2[(long)(int)r0.x * 64 + lane];
        unsigned g1 = Hb2[(long)(int)r1.x * 64 + lane];
        unsigned g2 = Hb2[(long)(int)r2.x * 64 + lane];
        unsigned g3 = Hb2[(long)(int)r3.x * 64 + lane];
        d0 += p0; ax0 += p0 * bflo(g0); ay0 += p0 * bfhi(g0);
        d1 += p1; ax1 += p1 * bflo(g1); ay1 += p1 * bfhi(g1);
        d2 += p2; ax2 += p2 * bflo(g2); ay2 += p2 * bfhi(g2);
        d3 += p3; ax3 += p3 * bflo(g3); ay3 += p3 * bfhi(g3);
    }
    for (; k < re; k++) {
        uint4 r0 = recbuf[k];
        float p0 = pe_of(r0, hh);
        unsigned g0 = Hb2[(long)(int)r0.x * 64 + lane];
        d0 += p0; ax0 += p0 * bflo(g0); ay0 += p0 * bfhi(g0);
    }
    float denom = (d0 + d1) + (d2 + d3);
    float ax = (ax0 + ax1) + (ax2 + ax3);
    float ay = (ay0 + ay1) + (ay2 + ay3);

    float2 b2 = ((const float2*)bias)[lane];
    float inv = 1.0f / (denom + 1e-16f);
    float o0 = ax * inv + b2.x;
    float o1 = ay * inv + b2.y;
    float g0 = 0.5f * o0 * (1.0f + erff(o0 * 0.70710678118654752f));
    float g1 = 0.5f * o1 * (1.0f + erff(o1 * 0.70710678118654752f));

    float s1 = g0 + g1, s2 = g0 * g0 + g1 * g1;
#pragma unroll
    for (int msk = 1; msk < 64; msk <<= 1) {
        s1 += __shfl_xor(s1, msk);
        s2 += __shfl_xor(s2, msk);
    }
    float mean = s1 * (1.0f / 128.0f);
    float var = s2 * (1.0f / 128.0f) - mean * mean;
    float rstd = rsqrtf(var + LN_EPS);
    float2 gm2 = ((const float2*)gamma)[lane];
    float2 bt2 = ((const float2*)beta)[lane];
    float f0 = (g0 - mean) * rstd * gm2.x + bt2.x;
    float f1 = (g1 - mean) * rstd * gm2.y + bt2.y;

    float2 xv = ((const float2*)X)[(long)node * 64 + lane];
    float2 ov;
    ov.x = f0 + xv.x;
    ov.y = f1 + xv.y;
    ((float2*)out)[(long)node * 64 + lane] = ov;
}

// ---------------- launch ----------------

extern "C" void kernel_launch(void* const* d_in, const int* in_sizes, int n_in,
                              void* d_out, int out_size, void* d_ws, size_t ws_size,
                              hipStream_t stream) {
    const float* x    = (const float*)d_in[0];
    const int*   ei   = (const int*)d_in[1];
    const float* W    = (const float*)d_in[2];
    const float* attS = (const float*)d_in[3];
    const float* attD = (const float*)d_in[4];
    const float* bias = (const float*)d_in[5];
    const float* gamma= (const float*)d_in[6];
    const float* beta = (const float*)d_in[7];
    float* out = (float*)d_out;

    int n = in_sizes[0] / DD;      // 50000
    int E = in_sizes[1] / 2;       // 600000
    int nb = (n + 255) / 256;      // 196 writeoff blocks
    int eb = (E + 255) / 256;      // 2344
    int zb = (n + 1023) / 1024;    // 49 deg-zero blocks

    char* ws = (char*)d_ws;
    size_t off = 0;
    auto alloc = [&](size_t bytes) -> void* {
        void* p = ws + off;
        off = (off + bytes + 255) & ~(size_t)255;
        return p;
    };
    unsigned short* Hb  = (unsigned short*)alloc((size_t)n * DD * 2);
    unsigned short* WTb = (unsigned short*)alloc((size_t)DD * DD * 2);
    float* aS       = (float*)alloc((size_t)n * HH * 4);
    float* aD       = (float*)alloc((size_t)n * HH * 4);
    float* pSelf    = (float*)alloc((size_t)n * HH * 4);
    int*   deg      = (int*)alloc((size_t)n * 4);
    int*   rowstart = (int*)alloc((size_t)(n + 1) * 4);
    int*   cursor   = (int*)alloc((size_t)n * 4);
    uint4* rec      = (uint4*)alloc((size_t)E * 16);
    int*   bpart    = (int*)alloc((size_t)nb * 4);

    wtrans_zero<<<8 + zb + 1, 256, 0, stream>>>(W, WTb, deg, bpart, n, nb, zb);
    count_kernel<<<eb, 256, 0, stream>>>(ei, deg, bpart, E);
    writeoff_kernel<<<nb, 256, 0, stream>>>(deg, bpart, rowstart, cursor, n, E);

    gemm_mfma<<<(n + 63) / 64, 256, 0, stream>>>(x, WTb, attS, attD, Hb, aS, aD, pSelf, n);

    fill_kernel<<<eb, 256, 0, stream>>>(ei, aS, aD, cursor, rec, E);

    agg_kernel<<<(n + 3) / 4, 256, 0, stream>>>((const unsigned*)Hb, pSelf, rec,
                                                rowstart, x, bias, gamma, beta, out, n);
}

// Round 12
// 203.843 us; speedup vs baseline: 2.6267x; 2.6267x over previous
//
#include <hip/hip_runtime.h>
#include <hip/hip_bf16.h>
#include <math.h>

#define DD 128
#define HH 4
#define NEG_SLOPE 0.2f
#define LN_EPS 1e-5f

typedef __attribute__((ext_vector_type(8))) short bf16x8;
typedef __attribute__((ext_vector_type(8))) unsigned short us16x8;
typedef __attribute__((ext_vector_type(4))) float f32x4;

__device__ __forceinline__ float lrelu(float e) { return fmaxf(e, NEG_SLOPE * e); }
__device__ __forceinline__ float bflo(unsigned u) { return __uint_as_float(u << 16); }
__device__ __forceinline__ float bfhi(unsigned u) { return __uint_as_float(u & 0xFFFF0000u); }
__device__ __forceinline__ unsigned short f2bf(float f) {
    return __builtin_bit_cast(unsigned short, __float2bfloat16(f));
}

// ---------------- W transpose + zero deg (one dispatch) ----------------
// blocks 0..7: WTb[col][k] = bf16(W[k][col]); blocks 8..: zero deg.

__global__ __launch_bounds__(256) void wtrans_zero(const float* __restrict__ W,
                                                   unsigned short* __restrict__ WTb,
                                                   int* __restrict__ deg, int n) {
    int b = blockIdx.x;
    int t = threadIdx.x;
    if (b < 8) {
        __shared__ float tile[16][128];
#pragma unroll
        for (int i = 0; i < 8; i++) {
            int flat = i * 256 + t;          // coalesced read of 16x128 slab
            int kk = flat >> 7, colc = flat & 127;
            tile[kk][colc] = W[(b * 16 + kk) * DD + colc];
        }
        __syncthreads();
        int colc = t & 127, half = t >> 7;
        us16x8 tmp;
#pragma unroll
        for (int kk = 0; kk < 8; kk++) tmp[kk] = f2bf(tile[half * 8 + kk][colc]);
        *(uint4*)&WTb[colc * DD + b * 16 + half * 8] = __builtin_bit_cast(uint4, tmp);
    } else {
        int base = (b - 8) * 1024 + t;
#pragma unroll
        for (int i = 0; i < 4; i++) {
            int idx = base + i * 256;
            if (idx < n) deg[idx] = 0;
        }
    }
}

// ---------------- CSR count: deg only (50000 addresses -> low contention) ----------------
// NOTE (round-10 lesson): do NOT also atomically bump a 196-entry bpart here —
// 600K atomics over 196 addresses serialized to 359us. bpart comes from
// partial_kernel below, contention-free.

__global__ __launch_bounds__(256) void count_kernel(const int* __restrict__ ei,
                                                    int* __restrict__ deg, int E) {
    int i = blockIdx.x * 256 + threadIdx.x;
    if (i < E) atomicAdd(&deg[ei[E + i]], 1);   // dst = ei[1][i]
}

// per-writeoff-block partial sums of deg (coalesced, no atomics)
__global__ __launch_bounds__(256) void partial_kernel(const int* __restrict__ deg,
                                                      int* __restrict__ bpart, int n) {
    __shared__ int r[4];
    int i = blockIdx.x * 256 + threadIdx.x;
    int v = (i < n) ? deg[i] : 0;
#pragma unroll
    for (int m = 1; m < 64; m <<= 1) v += __shfl_xor(v, m);
    if ((threadIdx.x & 63) == 0) r[threadIdx.x >> 6] = v;
    __syncthreads();
    if (threadIdx.x == 0) bpart[blockIdx.x] = r[0] + r[1] + r[2] + r[3];
}

// ---------------- writeoff: self-scan of bpart + in-block scan of deg ----------------

__global__ __launch_bounds__(256) void writeoff_kernel(const int* __restrict__ deg,
                                                       const int* __restrict__ bpart,
                                                       int* __restrict__ rowstart,
                                                       int* __restrict__ cursor, int n, int E) {
    __shared__ int addsh;
    __shared__ int ws[4];
    int t = threadIdx.x;
    // wave 0: exclusive prefix of bpart over preceding blocks
    if (t < 64) {
        int s = 0;
        for (int i = t; i < blockIdx.x; i += 64) s += bpart[i];
#pragma unroll
        for (int m = 1; m < 64; m <<= 1) s += __shfl_xor(s, m);
        if (t == 0) addsh = s;
    }
    int i = blockIdx.x * 256 + t;
    int v = (i < n) ? deg[i] : 0;
    int x = v;
#pragma unroll
    for (int m = 1; m < 64; m <<= 1) {
        int y = __shfl_up(x, m);
        if ((t & 63) >= m) x += y;
    }
    if ((t & 63) == 63) ws[t >> 6] = x;
    __syncthreads();
    int add = addsh;
    for (int w = 0; w < (t >> 6); w++) add += ws[w];
    int excl = x - v + add;
    if (i < n) { rowstart[i] = excl; cursor[i] = excl; }
    if (i == 0) rowstart[n] = E;
}

// fill CSR: one 16B record per edge {src, pe01(bf16x2), pe23(bf16x2), 0}
// pe = exp(lrelu(aS[src]+aD[dst])), unnormalized (|logit|<=~6 -> f32 exp safe;
// softmax is shift-invariant so no max pass needed).
__global__ __launch_bounds__(256) void fill_kernel(const int* __restrict__ ei,
                            const float* __restrict__ aS, const float* __restrict__ aD,
                            int* __restrict__ cursor, uint4* __restrict__ recbuf, int E) {
    int i = blockIdx.x * 256 + threadIdx.x;
    if (i >= E) return;
    int s = ei[i];
    int d = ei[E + i];
    int pos = atomicAdd(&cursor[d], 1);
    float4 sv = ((const float4*)aS)[s];
    float4 dv = ((const float4*)aD)[d];
    float p0 = __expf(lrelu(sv.x + dv.x));
    float p1 = __expf(lrelu(sv.y + dv.y));
    float p2 = __expf(lrelu(sv.z + dv.z));
    float p3 = __expf(lrelu(sv.w + dv.w));
    uint4 rec;
    rec.x = (unsigned)s;
    rec.y = (unsigned)f2bf(p0) | ((unsigned)f2bf(p1) << 16);
    rec.z = (unsigned)f2bf(p2) | ((unsigned)f2bf(p3) << 16);
    rec.w = 0;
    recbuf[pos] = rec;
}

// ---------------- MFMA GEMM + register-only fused logits ----------------
// Hb(bf16) = X @ W (round-2-verified core, direct scattered Hb stores).
// Logits fused via cross-lane shfl reduction over acc registers (NO LDS reuse):
// lane (q,l15) holds acc[c][r] = D[R+q*4+r][c*16+l15]; head of col c*16+l15 is c>>1.

__global__ __launch_bounds__(256) void gemm_mfma(const float* __restrict__ X,
                                                 const unsigned short* __restrict__ WTb,
                                                 const float* __restrict__ attS,
                                                 const float* __restrict__ attD,
                                                 unsigned short* __restrict__ Hb,
                                                 float* __restrict__ aS,
                                                 float* __restrict__ aD,
                                                 float* __restrict__ pSelf, int n) {
    __shared__ unsigned short lds[DD * DD];   // 32 KB, [col][k] bf16, XOR-swizzled
    int t = threadIdx.x;
    const uint4* src = (const uint4*)WTb;
#pragma unroll
    for (int i = 0; i < 8; i++) {
        int b = i * 256 + t;                  // 16B block index
        uint4 v = src[b];
        int byteaddr = b * 16;
        int col = b >> 4;
        int swz = byteaddr ^ ((col & 15) << 4);
        *(uint4*)((char*)lds + swz) = v;
    }
    __syncthreads();

    int w = t >> 6, l = t & 63;
    int R = blockIdx.x * 64 + w * 16;
    int l15 = l & 15, q = l >> 4;
    int rclamp = min(R + l15, n - 1);

    f32x4 acc[8];
#pragma unroll
    for (int c = 0; c < 8; c++) acc[c] = (f32x4){0.f, 0.f, 0.f, 0.f};

#pragma unroll
    for (int ks = 0; ks < 4; ks++) {
        // A-frag: row = l&15, k = ks*32 + q*8 + i (8 contiguous k per lane)
        const float* ap = X + (long)rclamp * DD + ks * 32 + q * 8;
        float4 a0 = *(const float4*)ap;
        float4 a1 = *(const float4*)(ap + 4);
        bf16x8 af;
        af[0] = (short)f2bf(a0.x); af[1] = (short)f2bf(a0.y);
        af[2] = (short)f2bf(a0.z); af[3] = (short)f2bf(a0.w);
        af[4] = (short)f2bf(a1.x); af[5] = (short)f2bf(a1.y);
        af[6] = (short)f2bf(a1.z); af[7] = (short)f2bf(a1.w);
#pragma unroll
        for (int c = 0; c < 8; c++) {
            int col = c * 16 + l15;
            int byteaddr = col * 256 + ks * 64 + q * 16;
            int swz = byteaddr ^ ((col & 15) << 4);
            bf16x8 bfr = *(const bf16x8*)((const char*)lds + swz);
            acc[c] = __builtin_amdgcn_mfma_f32_16x16x32_bf16(af, bfr, acc[c], 0, 0, 0);
        }
    }

    // Hb store (verified round-2 path): col = c*16+l15, row = R + q*4 + r
    int rowbase = R + q * 4;
#pragma unroll
    for (int c = 0; c < 8; c++) {
        int colw = c * 16 + l15;
#pragma unroll
        for (int r = 0; r < 4; r++) {
            int orow = rowbase + r;
            if (orow < n) Hb[(long)orow * DD + colw] = f2bf(acc[c][r]);
        }
    }

    // ---- fused logits: register-only, all indices compile-time ----
    float attSl[8], attDl[8];
#pragma unroll
    for (int h = 0; h < 4; h++) {
        attSl[2 * h]     = attS[h * 32 + l15];        // col c=2h   -> 32h+l15
        attSl[2 * h + 1] = attS[h * 32 + 16 + l15];   // col c=2h+1 -> 32h+16+l15
        attDl[2 * h]     = attD[h * 32 + l15];
        attDl[2 * h + 1] = attD[h * 32 + 16 + l15];
    }
    float sA[4][4], sD[4][4];   // [r][h], unrolled indices only
#pragma unroll
    for (int r = 0; r < 4; r++)
#pragma unroll
        for (int h = 0; h < 4; h++) {
            sA[r][h] = acc[2 * h][r] * attSl[2 * h] + acc[2 * h + 1][r] * attSl[2 * h + 1];
            sD[r][h] = acc[2 * h][r] * attDl[2 * h] + acc[2 * h + 1][r] * attDl[2 * h + 1];
        }
    // reduce over the 16-lane l15 group (masks 1,2,4,8 stay inside the group)
#pragma unroll
    for (int m = 1; m < 16; m <<= 1)
#pragma unroll
        for (int r = 0; r < 4; r++)
#pragma unroll
            for (int h = 0; h < 4; h++) {
                sA[r][h] += __shfl_xor(sA[r][h], m);
                sD[r][h] += __shfl_xor(sD[r][h], m);
            }
    // writer lane l15==r stores row R + q*4 + r (float4 over heads)
#pragma unroll
    for (int r = 0; r < 4; r++) {
        if (l15 == r) {
            int node = rowbase + r;
            if (node < n) {
                float4 s4 = make_float4(sA[r][0], sA[r][1], sA[r][2], sA[r][3]);
                float4 d4 = make_float4(sD[r][0], sD[r][1], sD[r][2], sD[r][3]);
                float4 p4;
                p4.x = __expf(lrelu(s4.x + d4.x));
                p4.y = __expf(lrelu(s4.y + d4.y));
                p4.z = __expf(lrelu(s4.z + d4.z));
                p4.w = __expf(lrelu(s4.w + d4.w));
                *(float4*)&aS[node * HH] = s4;
                *(float4*)&aD[node * HH] = d4;
                *(float4*)&pSelf[node * HH] = p4;
            }
        }
    }
}

// ---------------- aggregation + softmax-normalize + GELU + LN + residual ----------------
// ONE wave per node; lane owns channels (2*lane, 2*lane+1); head = lane>>4. Unroll-4.
// Edge stream: one uniform 16B record per edge (broadcast load).

__device__ __forceinline__ float pe_of(uint4 r, int hh) {
    unsigned wd = (hh & 2) ? r.z : r.y;
    return (hh & 1) ? bfhi(wd) : bflo(wd);
}

__global__ __launch_bounds__(256) void agg_kernel(const unsigned* __restrict__ Hb2,
                                                  const float* __restrict__ pSelf,
                                                  const uint4* __restrict__ recbuf,
                                                  const int* __restrict__ rowstart,
                                                  const float* __restrict__ X,
                                                  const float* __restrict__ bias,
                                                  const float* __restrict__ gamma,
                                                  const float* __restrict__ beta,
                                                  float* __restrict__ out, int n) {
    int node = blockIdx.x * 4 + (threadIdx.x >> 6);
    if (node >= n) return;                 // wave-uniform exit; no barriers used
    int lane = threadIdx.x & 63;
    int hh = lane >> 4;

    int rs = rowstart[node];
    int re = rowstart[node + 1];

    float p = pSelf[node * HH + hh];
    unsigned hv = Hb2[(long)node * 64 + lane];
    float d0 = p, ax0 = p * bflo(hv), ay0 = p * bfhi(hv);
    float d1 = 0.f, ax1 = 0.f, ay1 = 0.f;
    float d2 = 0.f, ax2 = 0.f, ay2 = 0.f;
    float d3 = 0.f, ax3 = 0.f, ay3 = 0.f;

    int k = rs;
    for (; k + 4 <= re; k += 4) {
        uint4 r0 = recbuf[k];
        uint4 r1 = recbuf[k + 1];
        uint4 r2 = recbuf[k + 2];
        uint4 r3 = recbuf[k + 3];
        float p0 = pe_of(r0, hh), p1 = pe_of(r1, hh);
        float p2 = pe_of(r2, hh), p3 = pe_of(r3, hh);
        unsigned g0 = Hb2[(long)(int)r0.x * 64 + lane];
        unsigned g1 = Hb2[(long)(int)r1.x * 64 + lane];
        unsigned g2 = Hb2[(long)(int)r2.x * 64 + lane];
        unsigned g3 = Hb2[(long)(int)r3.x * 64 + lane];
        d0 += p0; ax0 += p0 * bflo(g0); ay0 += p0 * bfhi(g0);
        d1 += p1; ax1 += p1 * bflo(g1); ay1 += p1 * bfhi(g1);
        d2 += p2; ax2 += p2 * bflo(g2); ay2 += p2 * bfhi(g2);
        d3 += p3; ax3 += p3 * bflo(g3); ay3 += p3 * bfhi(g3);
    }
    for (; k < re; k++) {
        uint4 r0 = recbuf[k];
        float p0 = pe_of(r0, hh);
        unsigned g0 = Hb2[(long)(int)r0.x * 64 + lane];
        d0 += p0; ax0 += p0 * bflo(g0); ay0 += p0 * bfhi(g0);
    }
    float denom = (d0 + d1) + (d2 + d3);
    float ax = (ax0 + ax1) + (ax2 + ax3);
    float ay = (ay0 + ay1) + (ay2 + ay3);

    float2 b2 = ((const float2*)bias)[lane];
    float inv = 1.0f / (denom + 1e-16f);
    float o0 = ax * inv + b2.x;
    float o1 = ay * inv + b2.y;
    float g0 = 0.5f * o0 * (1.0f + erff(o0 * 0.70710678118654752f));
    float g1 = 0.5f * o1 * (1.0f + erff(o1 * 0.70710678118654752f));

    float s1 = g0 + g1, s2 = g0 * g0 + g1 * g1;
#pragma unroll
    for (int msk = 1; msk < 64; msk <<= 1) {
        s1 += __shfl_xor(s1, msk);
        s2 += __shfl_xor(s2, msk);
    }
    float mean = s1 * (1.0f / 128.0f);
    float var = s2 * (1.0f / 128.0f) - mean * mean;
    float rstd = rsqrtf(var + LN_EPS);
    float2 gm2 = ((const float2*)gamma)[lane];
    float2 bt2 = ((const float2*)beta)[lane];
    float f0 = (g0 - mean) * rstd * gm2.x + bt2.x;
    float f1 = (g1 - mean) * rstd * gm2.y + bt2.y;

    float2 xv = ((const float2*)X)[(long)node * 64 + lane];
    float2 ov;
    ov.x = f0 + xv.x;
    ov.y = f1 + xv.y;
    ((float2*)out)[(long)node * 64 + lane] = ov;
}

// ---------------- launch ----------------

extern "C" void kernel_launch(void* const* d_in, const int* in_sizes, int n_in,
                              void* d_out, int out_size, void* d_ws, size_t ws_size,
                              hipStream_t stream) {
    const float* x    = (const float*)d_in[0];
    const int*   ei   = (const int*)d_in[1];
    const float* W    = (const float*)d_in[2];
    const float* attS = (const float*)d_in[3];
    const float* attD = (const float*)d_in[4];
    const float* bias = (const float*)d_in[5];
    const float* gamma= (const float*)d_in[6];
    const float* beta = (const float*)d_in[7];
    float* out = (float*)d_out;

    int n = in_sizes[0] / DD;      // 50000
    int E = in_sizes[1] / 2;       // 600000
    int nb = (n + 255) / 256;      // 196 writeoff blocks
    int eb = (E + 255) / 256;      // 2344
    int zb = (n + 1023) / 1024;    // 49 deg-zero blocks

    char* ws = (char*)d_ws;
    size_t off = 0;
    auto alloc = [&](size_t bytes) -> void* {
        void* p = ws + off;
        off = (off + bytes + 255) & ~(size_t)255;
        return p;
    };
    unsigned short* Hb  = (unsigned short*)alloc((size_t)n * DD * 2);
    unsigned short* WTb = (unsigned short*)alloc((size_t)DD * DD * 2);
    float* aS       = (float*)alloc((size_t)n * HH * 4);
    float* aD       = (float*)alloc((size_t)n * HH * 4);
    float* pSelf    = (float*)alloc((size_t)n * HH * 4);
    int*   deg      = (int*)alloc((size_t)n * 4);
    int*   rowstart = (int*)alloc((size_t)(n + 1) * 4);
    int*   cursor   = (int*)alloc((size_t)n * 4);
    uint4* rec      = (uint4*)alloc((size_t)E * 16);
    int*   bpart    = (int*)alloc((size_t)nb * 4);

    wtrans_zero<<<8 + zb, 256, 0, stream>>>(W, WTb, deg, n);
    count_kernel<<<eb, 256, 0, stream>>>(ei, deg, E);
    partial_kernel<<<nb, 256, 0, stream>>>(deg, bpart, n);
    writeoff_kernel<<<nb, 256, 0, stream>>>(deg, bpart, rowstart, cursor, n, E);

    gemm_mfma<<<(n + 63) / 64, 256, 0, stream>>>(x, WTb, attS, attD, Hb, aS, aD, pSelf, n);

    fill_kernel<<<eb, 256, 0, stream>>>(ei, aS, aD, cursor, rec, E);

    agg_kernel<<<(n + 3) / 4, 256, 0, stream>>>((const unsigned*)Hb, pSelf, rec,
                                                rowstart, x, bias, gamma, beta, out, n);
}